// Round 14
// baseline (495.913 us; speedup 1.0000x reference)
//
#include <hip/hip_runtime.h>

#define N_TOK 8192
#define DIM   1024
#define HID   4096
#define NEXP  4
#define MAXT  68             // max 256-row m-tiles: 64 + 4 alignment pads
#define NSLOT (MAXT*256)

typedef __attribute__((ext_vector_type(8))) _Float16 f16x8;
typedef __attribute__((ext_vector_type(4))) _Float16 f16x4;
typedef __attribute__((ext_vector_type(4))) float    f32x4;

__device__ __forceinline__ float gelu_erf(float v){
    return 0.5f * v * (1.0f + erff(v * 0.70710678118654752440f));
}
__device__ __forceinline__ float gelu_tanh(float v){
    float u = 0.7978845608028654f * v * (1.0f + 0.044715f * v * v);
    float e = __expf(2.0f * u);
    float t = 1.0f - 2.0f / (e + 1.0f);
    return 0.5f * v * (1.0f + t);
}

#define GLDS16(g, s) __builtin_amdgcn_global_load_lds( \
    (const __attribute__((address_space(1))) void*)(g), \
    (__attribute__((address_space(3))) void*)(s), 16, 0, 0)

#define BARRIER() do{ __builtin_amdgcn_s_barrier(); asm volatile("" ::: "memory"); }while(0)
#define VMCNTN(n) asm volatile("s_waitcnt vmcnt(" #n ")" ::: "memory")

// ---------------- fused transpose: w1 [E][D][H]->[E][H][D], w2 [E][H][D]->[E][D][H]
__global__ void k_transpose_all(const float* __restrict__ w1, const float* __restrict__ w2,
                                _Float16* __restrict__ w1t, _Float16* __restrict__ w2t){
    __shared__ float tile[32][33];
    int bid = blockIdx.x;            // 0..32767
    int z = bid >> 12;               // 8 slices of 4096 tiles
    int i = bid & 4095;
    const float* s; _Float16* d; int R, C, bx, by;
    if (z < 4){ R = DIM; C = HID; bx = i & 127; by = i >> 7;
        s = w1 + (size_t)z * R * C; d = w1t + (size_t)z * R * C; }
    else      { R = HID; C = DIM; bx = i & 31;  by = i >> 5;
        s = w2 + (size_t)(z-4) * R * C; d = w2t + (size_t)(z-4) * R * C; }
    int tx = threadIdx.x & 31, ty = threadIdx.x >> 5;   // 32 x 8
    int c0 = bx*32, r0 = by*32;
    #pragma unroll
    for (int rr = 0; rr < 32; rr += 8)
        tile[ty+rr][tx] = s[(size_t)(r0+ty+rr)*C + c0+tx];
    __syncthreads();
    #pragma unroll
    for (int rr = 0; rr < 32; rr += 8)
        d[(size_t)(c0+ty+rr)*R + r0+tx] = (_Float16)tile[tx][ty+rr];
}

// ---------------- gelu(b1) (erf form — must match reference c') -------------
__global__ void k_gb1(const float* __restrict__ b1, float* __restrict__ gb1, int n){
    int i = blockIdx.x*256 + threadIdx.x;
    if (i < n) gb1[i] = gelu_erf(b1[i]);
}

// ---------------- c' partials ----------------
__global__ void k_cprime_part(const float* __restrict__ w2, const float* __restrict__ gb1,
                              float* __restrict__ part){
    int d = blockIdx.x*256 + threadIdx.x;
    int p = blockIdx.y, e = blockIdx.z;
    float acc = 0.f;
    int h0 = p*(HID/8);
    for (int h = h0; h < h0 + HID/8; ++h)
        acc += gb1[e*HID + h] * w2[((size_t)e*HID + h)*DIM + d];
    part[(size_t)(e*8 + p)*DIM + d] = acc;
}

// ---------------- reduce partials -> cprime, csum ----------------
__global__ void k_cfinal(const float* __restrict__ part, const float* __restrict__ b2,
                         float* __restrict__ cprime, float* __restrict__ csum){
    int d = blockIdx.x*256 + threadIdx.x;
    float cs = 0.f;
    #pragma unroll
    for (int e = 0; e < NEXP; ++e){
        float a = 0.f;
        #pragma unroll
        for (int p = 0; p < 8; ++p) a += part[(size_t)(e*8 + p)*DIM + d];
        cprime[e*DIM + d] = a;
        cs += a + b2[e*DIM + d];
    }
    csum[d] = cs;
}

// ---------------- routing logits + x->f16 (atomic-free) ----------------
__global__ void k_route(const float* __restrict__ x, const float* __restrict__ wr,
                        const float* __restrict__ br, _Float16* __restrict__ xb,
                        int* __restrict__ expi, float* __restrict__ gatev){
    int lane = threadIdx.x & 63, w = threadIdx.x >> 6;
    int t = blockIdx.x*4 + w;
    const float4* x4  = (const float4*)(x + (size_t)t*DIM);
    const float4* wr4 = (const float4*)wr;
    f16x4* xb4 = (f16x4*)(xb + (size_t)t*DIM);
    float a0=0.f, a1=0.f, a2=0.f, a3=0.f;
    #pragma unroll
    for (int it = 0; it < 4; ++it){
        int q = it*64 + lane;
        float4 v = x4[q];
        f16x4 h; h[0]=(_Float16)v.x; h[1]=(_Float16)v.y; h[2]=(_Float16)v.z; h[3]=(_Float16)v.w;
        xb4[q] = h;
        int d = q*4;
        float4 w0 = wr4[d], w1v = wr4[d+1], w2v = wr4[d+2], w3v = wr4[d+3];
        a0 += v.x*w0.x + v.y*w1v.x + v.z*w2v.x + v.w*w3v.x;
        a1 += v.x*w0.y + v.y*w1v.y + v.z*w2v.y + v.w*w3v.y;
        a2 += v.x*w0.z + v.y*w1v.z + v.z*w2v.z + v.w*w3v.z;
        a3 += v.x*w0.w + v.y*w1v.w + v.z*w2v.w + v.w*w3v.w;
    }
    #pragma unroll
    for (int off = 32; off; off >>= 1){
        a0 += __shfl_xor(a0, off);
        a1 += __shfl_xor(a1, off);
        a2 += __shfl_xor(a2, off);
        a3 += __shfl_xor(a3, off);
    }
    if (lane == 0){
        float v[4] = {a0+br[0], a1+br[1], a2+br[2], a3+br[3]};
        int e0 = 0; float v0 = v[0];
        #pragma unroll
        for (int e = 1; e < 4; ++e) if (v[e] > v0){ v0 = v[e]; e0 = e; }
        int e1 = -1; float v1 = -1e30f;
        #pragma unroll
        for (int e = 0; e < 4; ++e) if (e != e0 && v[e] > v1){ v1 = v[e]; e1 = e; }
        float ex = expf(v1 - v0);
        float g0 = 1.f/(1.f+ex), g1 = ex/(1.f+ex);
        expi[2*t] = e0; expi[2*t+1] = e1;
        gatev[2*t] = g0; gatev[2*t+1] = g1;
    }
}

// ---------------- global compaction + pad fill ------------------------------
__global__ __launch_bounds__(1024)
void k_compact(const int* __restrict__ expi, const float* __restrict__ gatev,
               int* __restrict__ tbase, int* __restrict__ tokl, int* __restrict__ slotof){
    const int e = blockIdx.x;
    const int tid = threadIdx.x, lane = tid & 63, wv = tid >> 6;
    __shared__ int w4[16][4];
    __shared__ int wsum[16];
    int c0=0,c1=0,c2=0,c3=0;
    const int base = tid*16;
    #pragma unroll
    for (int i = 0; i < 16; ++i){
        int v = expi[base+i];
        c0 += (v==0); c1 += (v==1); c2 += (v==2); c3 += (v==3);
    }
    int mysel = (e==0)?c0:(e==1)?c1:(e==2)?c2:c3;
    int r0=c0, r1=c1, r2=c2, r3=c3;
    #pragma unroll
    for (int off = 32; off; off >>= 1){
        r0 += __shfl_xor(r0,off); r1 += __shfl_xor(r1,off);
        r2 += __shfl_xor(r2,off); r3 += __shfl_xor(r3,off);
    }
    if (lane == 0){ w4[wv][0]=r0; w4[wv][1]=r1; w4[wv][2]=r2; w4[wv][3]=r3; }
    int sc = mysel;
    #pragma unroll
    for (int off = 1; off < 64; off <<= 1){
        int tv = __shfl_up(sc, off);
        if (lane >= off) sc += tv;
    }
    if (lane == 63) wsum[wv] = sc;
    __syncthreads();
    int t0=0,t1=0,t2=0,t3=0;
    #pragma unroll
    for (int i = 0; i < 16; ++i){ t0+=w4[i][0]; t1+=w4[i][1]; t2+=w4[i][2]; t3+=w4[i][3]; }
    int n0=(t0+255)>>8, n1=(t1+255)>>8, n2=(t2+255)>>8, n3=(t3+255)>>8;
    int tb1=n0, tb2=n0+n1, tb3=n0+n1+n2, tb4=n0+n1+n2+n3;
    int mybase = ((e==0)?0:(e==1)?tb1:(e==2)?tb2:tb3)*256;
    int cnt_e  = (e==0)?t0:(e==1)?t1:(e==2)?t2:t3;
    int segrows= ((e==0)?n0:(e==1)?n1:(e==2)?n2:n3)*256;
    int wbase = 0;
    for (int i = 0; i < wv; ++i) wbase += wsum[i];
    int myoff = mybase + wbase + sc - mysel;
    #pragma unroll
    for (int i = 0; i < 16; ++i){
        int j = base + i;
        if (expi[j] == e){
            tokl[myoff]  = j >> 1;
            slotof[j] = myoff;
            myoff++;
        }
    }
    for (int i = cnt_e + tid; i < segrows; i += 1024) tokl[mybase + i] = 0;
    if (e == 0 && tid == 0){
        tbase[0]=0; tbase[1]=tb1; tbase[2]=tb2; tbase[3]=tb3; tbase[4]=tb4;
    }
}

// ========== unified GEMM: 128x128x32, 4 waves, 4 blocks/CU ==================
// LDS buf q at q*16384: A[64p][128B] @0 (8KB), B @8192. 32KB/block total ->
// 4 blocks/CU resident (launch_bounds(256,4), VGPR ~70).
// Packed-row swizzle (BK=32): physical row p = row>>1 holds both logical rows
// 2p,2p+1 as 8 chunk-slots; slot s' = (row&1)*4 + kc, stored at s = s'^(p&7).
// Conflict-free ds_read_b128 (8 distinct slots across the 8 p's of a column
// read); stage dest stays lane-linear, source computes the inverse map.
// 2-phase FIFO ledger per wave (4 glds/K-tile: A2+B0 1+B1 1):
//  P1: read A,B0(t) | stage B1(t+1)->cur^1 | vmcnt(4) bar | 8 MFMA | bar
//  P2: read B1(t)   | stage A,B0(t+2)->cur | vmcnt(4) bar | 8 MFMA | bar
//  tails: P1 t=NK-1: 0; P2 t=NK-2: 1, t=NK-1: 0. Prologue 7 loads, vmcnt(4).
// Simulated: each pair confirms exactly the next phase's reads; overwrites
// >=1 barrier after last read.

#define G_MFMA(RA, RB, NB) \
  _Pragma("unroll") for (int mf_ = 0; mf_ < 4; ++mf_) \
    _Pragma("unroll") for (int nf_ = 0; nf_ < 2; ++nf_) \
        acc[mf_][NB+nf_] = __builtin_amdgcn_mfma_f32_16x16x32_f16( \
            RA[mf_], RB[nf_], acc[mf_][NB+nf_], 0, 0, 0)

#define G_LDA(CUR) \
  _Pragma("unroll") for (int mf_ = 0; mf_ < 4; ++mf_) \
      rA[mf_] = *(const f16x8*)(smem + (CUR)*16384 + rbA[mf_])

#define G_LDB(DST, NB, CUR) \
  _Pragma("unroll") for (int nf_ = 0; nf_ < 2; ++nf_) \
      DST[nf_] = *(const f16x8*)(smem + (CUR)*16384 + rbB[NB+nf_])

#define STG_A(Q, KT) do{ \
    GLDS16(pA[0] + (size_t)(KT)*32, smem + (Q)*16384 + dA0); \
    GLDS16(pA[1] + (size_t)(KT)*32, smem + (Q)*16384 + dA1); }while(0)
#define STG_B0(Q, KT) GLDS16(pB0 + (size_t)(KT)*32, smem + (Q)*16384 + 8192 + dB0)
#define STG_B1(Q, KT) GLDS16(pB1 + (size_t)(KT)*32, smem + (Q)*16384 + 8192 + dB1)

template<int KDIM, int NDIM, bool G1>
__global__ __launch_bounds__(256, 4)
void k_gemm(const _Float16* __restrict__ Aglob, const _Float16* __restrict__ Bglob,
            const float* __restrict__ b1, const int* __restrict__ tokl,
            const int* __restrict__ tb, _Float16* __restrict__ Cout)
{
    extern __shared__ char smem[];
    const int NT = NDIM/128;                     // 32 (g1) / 8 (g2)
    const int M2 = 2*MAXT;                       // 136 m-tiles of 128 rows
    const int nwg = M2*NT;                       // div by 8
    const int logical = ((int)blockIdx.x & 7)*(nwg>>3) + ((int)blockIdx.x >> 3);
    const int band = logical / (M2*8);
    const int rr_  = logical % (M2*8);
    const int mt = rr_ >> 3, nt = band*8 + (rr_ & 7);
    if (mt >= 2*tb[4]) return;
    const int e = (mt >= 2*tb[1]) + (mt >= 2*tb[2]) + (mt >= 2*tb[3]);
    const int tid = (int)threadIdx.x;
    const int ln = tid & 63, wv = tid >> 6;      // 4 waves
    const int wr2 = wv >> 1, wc2 = wv & 1;       // 2M x 2N
    const int lr = ln & 15, lk = ln >> 4;
    const int NK = KDIM/32;

    // ---- stage sources: inverse of the packed-row swizzle, per lane
    const _Float16* pA[2];
    #pragma unroll
    for (int l = 0; l < 2; ++l){
        const int p  = (wv*2 + l)*8 + (ln >> 3);     // physical row 0..63
        const int sp = (ln & 7) ^ (p & 7);           // unswizzled slot
        const int row = 2*p + (sp >> 2);
        const int kc  = sp & 3;
        size_t arow;
        if constexpr (G1) arow = (size_t)tokl[mt*128 + row];
        else              arow = (size_t)(mt*128 + row);
        pA[l] = Aglob + arow*KDIM + kc*8;
    }
    const int dA0 = (wv*2+0)*1024 + 0;               // +ln*16 implicit in glds
    const int dA1 = (wv*2+1)*1024 + 0;
    const int pb0s = (wv & 1)*8 + (wv >> 1)*32;      // B0 p-start {0,8,32,40}
    const int pb1s = pb0s + 16;                      // B1 p-start {16,24,48,56}
    const _Float16* pB0; const _Float16* pB1;
    {
        const int p  = pb0s + (ln >> 3);
        const int sp = (ln & 7) ^ (p & 7);
        const int row = 2*p + (sp >> 2);
        const int kc  = sp & 3;
        pB0 = Bglob + ((size_t)e*NDIM + nt*128 + row)*KDIM + kc*8;
    }
    {
        const int p  = pb1s + (ln >> 3);
        const int sp = (ln & 7) ^ (p & 7);
        const int row = 2*p + (sp >> 2);
        const int kc  = sp & 3;
        pB1 = Bglob + ((size_t)e*NDIM + nt*128 + row)*KDIM + kc*8;
    }
    const int dB0 = pb0s*128;
    const int dB1 = pb1s*128;

    // ---- ds_read swizzled base offsets (frag: row, k-chunk lk)
    int rbA[4], rbB[4];
    #pragma unroll
    for (int mf = 0; mf < 4; ++mf){
        int row = wr2*64 + mf*16 + lr;
        int p = row >> 1, sp = (row & 1)*4 + lk;
        rbA[mf] = p*128 + (sp ^ (p & 7))*16;
    }
    #pragma unroll
    for (int nf = 0; nf < 4; ++nf){
        int row = wc2*64 + nf*16 + lr;
        int p = row >> 1, sp = (row & 1)*4 + lk;
        rbB[nf] = 8192 + p*128 + (sp ^ (p & 7))*16;
    }

    f32x4 acc[4][4];
    #pragma unroll
    for (int i = 0; i < 4; ++i)
        #pragma unroll
        for (int j = 0; j < 4; ++j) acc[i][j] = (f32x4){0.f,0.f,0.f,0.f};
    f16x8 rA[4], rB0[2], rB1[2];

    // ---- prologue FIFO: AB0(0):3, B1(0):1, AB0(1):3 ; confirm AB0(0)
    STG_A(0,0); STG_B0(0,0);
    STG_B1(0,0);
    STG_A(1,1); STG_B0(1,1);
    VMCNTN(4);
    BARRIER();

    for (int t = 0; t < NK; ++t){
        const int cur = t & 1;
        // P1: read A,B0(t); stage B1(t+1)->cur^1; pair confirms B1(t)
        G_LDA(cur); G_LDB(rB0, 0, cur);
        if (t+1 < NK){ STG_B1(cur^1, t+1); VMCNTN(4); } else { VMCNTN(0); }
        BARRIER();
        __builtin_amdgcn_s_setprio(1); G_MFMA(rA, rB0, 0); __builtin_amdgcn_s_setprio(0);
        BARRIER();
        // P2: read B1(t); stage A,B0(t+2)->cur; pair confirms AB0(t+1)
        G_LDB(rB1, 2, cur);
        if (t+2 < NK){ STG_A(cur, t+2); STG_B0(cur, t+2); VMCNTN(4); }
        else if (t+1 < NK){ VMCNTN(1); }
        else { VMCNTN(0); }
        BARRIER();
        __builtin_amdgcn_s_setprio(1); G_MFMA(rA, rB1, 2); __builtin_amdgcn_s_setprio(0);
        BARRIER();
    }

    // ---- epilogue
    if constexpr (G1){
        float bv[4];
        #pragma unroll
        for (int nf = 0; nf < 4; ++nf)
            bv[nf] = b1[e*NDIM + nt*128 + wc2*64 + nf*16 + lr];
        #pragma unroll
        for (int mf = 0; mf < 4; ++mf){
            int row = mt*128 + wr2*64 + mf*16 + lk*4;
            #pragma unroll
            for (int nf = 0; nf < 4; ++nf){
                int col = nt*128 + wc2*64 + nf*16 + lr;
                #pragma unroll
                for (int r = 0; r < 4; ++r)
                    Cout[(size_t)(row+r)*NDIM + col] = (_Float16)gelu_tanh(acc[mf][nf][r] + bv[nf]);
            }
        }
    } else {
        #pragma unroll
        for (int mf = 0; mf < 4; ++mf){
            int row = mt*128 + wr2*64 + mf*16 + lk*4;
            #pragma unroll
            for (int nf = 0; nf < 4; ++nf){
                int col = nt*128 + wc2*64 + nf*16 + lr;
                #pragma unroll
                for (int r = 0; r < 4; ++r)
                    Cout[(size_t)(row+r)*NDIM + col] = (_Float16)acc[mf][nf][r];
            }
        }
    }
}

// ---------------- final: out = csum + g0*(y0-c'0) + g1*(y1-c'1) -------------
__global__ void k_final(const int* __restrict__ expi, const float* __restrict__ gatev,
                        const int* __restrict__ slotof, const _Float16* __restrict__ ybuf,
                        const float* __restrict__ cprime, const float* __restrict__ csum,
                        float* __restrict__ out){
    int i = blockIdx.x*256 + threadIdx.x;
    int t = i >> 8;
    int dq = i & 255;
    int e0 = expi[2*t], e1 = expi[2*t+1];
    float g0 = gatev[2*t], g1 = gatev[2*t+1];
    int s0 = slotof[2*t], s1 = slotof[2*t+1];
    const float4* cp = (const float4*)cprime;
    float4 cs = ((const float4*)csum)[dq];
    float4 c0 = cp[e0*256 + dq], c1 = cp[e1*256 + dq];
    f16x4 y0 = ((const f16x4*)ybuf)[(size_t)s0*256 + dq];
    f16x4 y1 = ((const f16x4*)ybuf)[(size_t)s1*256 + dq];
    float4 r;
    r.x = cs.x + g0*((float)y0[0] - c0.x) + g1*((float)y1[0] - c1.x);
    r.y = cs.y + g0*((float)y0[1] - c0.y) + g1*((float)y1[1] - c1.y);
    r.z = cs.z + g0*((float)y0[2] - c0.z) + g1*((float)y1[2] - c1.z);
    r.w = cs.w + g0*((float)y0[3] - c0.w) + g1*((float)y1[3] - c1.w);
    ((float4*)out)[i] = r;
}

extern "C" void kernel_launch(void* const* d_in, const int* in_sizes, int n_in,
                              void* d_out, int out_size, void* d_ws, size_t ws_size,
                              hipStream_t stream){
    const float* x  = (const float*)d_in[0];
    const float* w1 = (const float*)d_in[1];
    const float* b1 = (const float*)d_in[2];
    const float* w2 = (const float*)d_in[3];
    const float* b2 = (const float*)d_in[4];
    const float* wr = (const float*)d_in[5];
    const float* br = (const float*)d_in[6];
    float* out = (float*)d_out;

    char* ws = (char*)d_ws;
    size_t o = 0;
    auto take = [&](size_t bytes)->char*{
        char* p = ws + o;
        o = (o + bytes + 255) & ~(size_t)255;
        return p;
    };
    _Float16* xb    = (_Float16*)take((size_t)N_TOK*DIM*2);        // 16.8 MB
    _Float16* w1t   = (_Float16*)take((size_t)NEXP*HID*DIM*2);     // 33.5 MB
    _Float16* w2t   = (_Float16*)take((size_t)NEXP*HID*DIM*2);     // 33.5 MB
    _Float16* hbuf  = (_Float16*)take((size_t)NSLOT*HID*2);        // 142.6 MB
    _Float16* ybuf  = (_Float16*)take((size_t)NSLOT*DIM*2);        // 35.7 MB
    float*    gb1   = (float*)take((size_t)NEXP*HID*4);
    float*    part  = (float*)take((size_t)NEXP*8*DIM*4);
    float*    cprime= (float*)take((size_t)NEXP*DIM*4);
    float*    csum  = (float*)take((size_t)DIM*4);
    int*      tbase = (int*)take(64);
    int*      expi  = (int*)take((size_t)N_TOK*2*4);
    float*    gatev = (float*)take((size_t)N_TOK*2*4);
    int*      slotof= (int*)take((size_t)N_TOK*2*4);
    int*      tokl  = (int*)take((size_t)NSLOT*4);
    (void)ws_size; (void)in_sizes; (void)n_in; (void)out_size;

    hipFuncSetAttribute(reinterpret_cast<const void*>(&k_gemm<DIM, HID, true>),
                        hipFuncAttributeMaxDynamicSharedMemorySize, 32768);
    hipFuncSetAttribute(reinterpret_cast<const void*>(&k_gemm<HID, DIM, false>),
                        hipFuncAttributeMaxDynamicSharedMemorySize, 32768);

    hipLaunchKernelGGL(k_transpose_all, dim3(32768), dim3(256), 0, stream, w1, w2, w1t, w2t);
    hipLaunchKernelGGL(k_gb1, dim3(NEXP*HID/256), dim3(256), 0, stream, b1, gb1, NEXP*HID);
    hipLaunchKernelGGL(k_cprime_part, dim3(DIM/256, 8, NEXP), dim3(256), 0, stream, w2, gb1, part);
    hipLaunchKernelGGL(k_cfinal, dim3(DIM/256), dim3(256), 0, stream, part, b2, cprime, csum);
    hipLaunchKernelGGL(k_route, dim3(N_TOK/4), dim3(256), 0, stream, x, wr, br, xb, expi, gatev);
    hipLaunchKernelGGL(k_compact, dim3(NEXP), dim3(1024), 0, stream, expi, gatev, tbase, tokl, slotof);
    hipLaunchKernelGGL((k_gemm<DIM, HID, true>), dim3(2*MAXT*(HID/128)), dim3(256), 32768, stream,
                       xb, w1t, b1, tokl, tbase, hbuf);
    hipLaunchKernelGGL((k_gemm<HID, DIM, false>), dim3(2*MAXT*(DIM/128)), dim3(256), 32768, stream,
                       hbuf, w2t, b1, tokl, tbase, ybuf);
    hipLaunchKernelGGL(k_final, dim3(N_TOK*DIM/4/256), dim3(256), 0, stream,
                       expi, gatev, slotof, ybuf, cprime, csum, out);
}

// Round 15
// 412.708 us; speedup vs baseline: 1.2016x; 1.2016x over previous
//
#include <hip/hip_runtime.h>

#define N_TOK 8192
#define DIM   1024
#define HID   4096
#define NEXP  4
#define MAXT  68             // max 256-row m-tiles: 64 + 4 alignment pads
#define NSLOT (MAXT*256)

typedef __attribute__((ext_vector_type(8))) _Float16 f16x8;
typedef __attribute__((ext_vector_type(4))) _Float16 f16x4;
typedef __attribute__((ext_vector_type(4))) float    f32x4;

__device__ __forceinline__ float gelu_erf(float v){
    return 0.5f * v * (1.0f + erff(v * 0.70710678118654752440f));
}
__device__ __forceinline__ float gelu_tanh(float v){
    float u = 0.7978845608028654f * v * (1.0f + 0.044715f * v * v);
    float e = __expf(2.0f * u);
    float t = 1.0f - 2.0f / (e + 1.0f);
    return 0.5f * v * (1.0f + t);
}

#define GLDS16(g, s) __builtin_amdgcn_global_load_lds( \
    (const __attribute__((address_space(1))) void*)(g), \
    (__attribute__((address_space(3))) void*)(s), 16, 0, 0)

#define BARRIER() do{ __builtin_amdgcn_s_barrier(); asm volatile("" ::: "memory"); }while(0)
#define VMCNTN(n) asm volatile("s_waitcnt vmcnt(" #n ")" ::: "memory")

// ---------------- fused transpose: w1 [E][D][H]->[E][H][D], w2 [E][H][D]->[E][D][H]
__global__ void k_transpose_all(const float* __restrict__ w1, const float* __restrict__ w2,
                                _Float16* __restrict__ w1t, _Float16* __restrict__ w2t){
    __shared__ float tile[32][33];
    int bid = blockIdx.x;            // 0..32767
    int z = bid >> 12;               // 8 slices of 4096 tiles
    int i = bid & 4095;
    const float* s; _Float16* d; int R, C, bx, by;
    if (z < 4){ R = DIM; C = HID; bx = i & 127; by = i >> 7;
        s = w1 + (size_t)z * R * C; d = w1t + (size_t)z * R * C; }
    else      { R = HID; C = DIM; bx = i & 31;  by = i >> 5;
        s = w2 + (size_t)(z-4) * R * C; d = w2t + (size_t)(z-4) * R * C; }
    int tx = threadIdx.x & 31, ty = threadIdx.x >> 5;   // 32 x 8
    int c0 = bx*32, r0 = by*32;
    #pragma unroll
    for (int rr = 0; rr < 32; rr += 8)
        tile[ty+rr][tx] = s[(size_t)(r0+ty+rr)*C + c0+tx];
    __syncthreads();
    #pragma unroll
    for (int rr = 0; rr < 32; rr += 8)
        d[(size_t)(c0+ty+rr)*R + r0+tx] = (_Float16)tile[tx][ty+rr];
}

// ---------------- gelu(b1) (erf form — must match reference c') -------------
__global__ void k_gb1(const float* __restrict__ b1, float* __restrict__ gb1, int n){
    int i = blockIdx.x*256 + threadIdx.x;
    if (i < n) gb1[i] = gelu_erf(b1[i]);
}

// ---------------- c'[e][d] = sum_h gb1[e][h] * w2t[e][d][h]  (f16 row-dot) --
__global__ void k_cprime_w(const _Float16* __restrict__ w2t, const float* __restrict__ gb1,
                           float* __restrict__ cprime){
    const int gw = blockIdx.x*4 + ((int)threadIdx.x >> 6);   // 0..4095
    const int e = gw >> 10, d = gw & 1023;
    const int lane = threadIdx.x & 63;
    const f16x8* row = (const f16x8*)(w2t + ((size_t)e*DIM + d)*HID);
    const float4* gb  = (const float4*)(gb1 + (size_t)e*HID);
    float acc = 0.f;
    #pragma unroll
    for (int it = 0; it < 8; ++it){
        int q = it*64 + lane;                 // 8-elem chunk index
        f16x8 v = row[q];
        float4 g0 = gb[q*2], g1 = gb[q*2+1];
        acc += (float)v[0]*g0.x + (float)v[1]*g0.y + (float)v[2]*g0.z + (float)v[3]*g0.w
             + (float)v[4]*g1.x + (float)v[5]*g1.y + (float)v[6]*g1.z + (float)v[7]*g1.w;
    }
    #pragma unroll
    for (int off = 32; off; off >>= 1) acc += __shfl_xor(acc, off);
    if (lane == 0) cprime[e*DIM + d] = acc;
}

// ---------------- csum[d] = sum_e (cprime[e][d] + b2[e][d]) -----------------
__global__ void k_csum(const float* __restrict__ cprime, const float* __restrict__ b2,
                       float* __restrict__ csum){
    int d = blockIdx.x*256 + threadIdx.x;
    float cs = 0.f;
    #pragma unroll
    for (int e = 0; e < NEXP; ++e) cs += cprime[e*DIM + d] + b2[e*DIM + d];
    csum[d] = cs;
}

// ---------------- routing logits + x->f16 (atomic-free) ----------------
__global__ void k_route(const float* __restrict__ x, const float* __restrict__ wr,
                        const float* __restrict__ br, _Float16* __restrict__ xb,
                        int* __restrict__ expi, float* __restrict__ gatev){
    int lane = threadIdx.x & 63, w = threadIdx.x >> 6;
    int t = blockIdx.x*4 + w;
    const float4* x4  = (const float4*)(x + (size_t)t*DIM);
    const float4* wr4 = (const float4*)wr;
    f16x4* xb4 = (f16x4*)(xb + (size_t)t*DIM);
    float a0=0.f, a1=0.f, a2=0.f, a3=0.f;
    #pragma unroll
    for (int it = 0; it < 4; ++it){
        int q = it*64 + lane;
        float4 v = x4[q];
        f16x4 h; h[0]=(_Float16)v.x; h[1]=(_Float16)v.y; h[2]=(_Float16)v.z; h[3]=(_Float16)v.w;
        xb4[q] = h;
        int d = q*4;
        float4 w0 = wr4[d], w1v = wr4[d+1], w2v = wr4[d+2], w3v = wr4[d+3];
        a0 += v.x*w0.x + v.y*w1v.x + v.z*w2v.x + v.w*w3v.x;
        a1 += v.x*w0.y + v.y*w1v.y + v.z*w2v.y + v.w*w3v.y;
        a2 += v.x*w0.z + v.y*w1v.z + v.z*w2v.z + v.w*w3v.z;
        a3 += v.x*w0.w + v.y*w1v.w + v.z*w2v.w + v.w*w3v.w;
    }
    #pragma unroll
    for (int off = 32; off; off >>= 1){
        a0 += __shfl_xor(a0, off);
        a1 += __shfl_xor(a1, off);
        a2 += __shfl_xor(a2, off);
        a3 += __shfl_xor(a3, off);
    }
    if (lane == 0){
        float v[4] = {a0+br[0], a1+br[1], a2+br[2], a3+br[3]};
        int e0 = 0; float v0 = v[0];
        #pragma unroll
        for (int e = 1; e < 4; ++e) if (v[e] > v0){ v0 = v[e]; e0 = e; }
        int e1 = -1; float v1 = -1e30f;
        #pragma unroll
        for (int e = 0; e < 4; ++e) if (e != e0 && v[e] > v1){ v1 = v[e]; e1 = e; }
        float ex = expf(v1 - v0);
        float g0 = 1.f/(1.f+ex), g1 = ex/(1.f+ex);
        expi[2*t] = e0; expi[2*t+1] = e1;
        gatev[2*t] = g0; gatev[2*t+1] = g1;
    }
}

// ---------------- global compaction + pad fill ------------------------------
__global__ __launch_bounds__(1024)
void k_compact(const int* __restrict__ expi, const float* __restrict__ gatev,
               int* __restrict__ tbase, int* __restrict__ tokl, int* __restrict__ slotof){
    const int e = blockIdx.x;
    const int tid = threadIdx.x, lane = tid & 63, wv = tid >> 6;
    __shared__ int w4[16][4];
    __shared__ int wsum[16];
    int c0=0,c1=0,c2=0,c3=0;
    const int base = tid*16;
    #pragma unroll
    for (int i = 0; i < 16; ++i){
        int v = expi[base+i];
        c0 += (v==0); c1 += (v==1); c2 += (v==2); c3 += (v==3);
    }
    int mysel = (e==0)?c0:(e==1)?c1:(e==2)?c2:c3;
    int r0=c0, r1=c1, r2=c2, r3=c3;
    #pragma unroll
    for (int off = 32; off; off >>= 1){
        r0 += __shfl_xor(r0,off); r1 += __shfl_xor(r1,off);
        r2 += __shfl_xor(r2,off); r3 += __shfl_xor(r3,off);
    }
    if (lane == 0){ w4[wv][0]=r0; w4[wv][1]=r1; w4[wv][2]=r2; w4[wv][3]=r3; }
    int sc = mysel;
    #pragma unroll
    for (int off = 1; off < 64; off <<= 1){
        int tv = __shfl_up(sc, off);
        if (lane >= off) sc += tv;
    }
    if (lane == 63) wsum[wv] = sc;
    __syncthreads();
    int t0=0,t1=0,t2=0,t3=0;
    #pragma unroll
    for (int i = 0; i < 16; ++i){ t0+=w4[i][0]; t1+=w4[i][1]; t2+=w4[i][2]; t3+=w4[i][3]; }
    int n0=(t0+255)>>8, n1=(t1+255)>>8, n2=(t2+255)>>8, n3=(t3+255)>>8;
    int tb1=n0, tb2=n0+n1, tb3=n0+n1+n2, tb4=n0+n1+n2+n3;
    int mybase = ((e==0)?0:(e==1)?tb1:(e==2)?tb2:tb3)*256;
    int cnt_e  = (e==0)?t0:(e==1)?t1:(e==2)?t2:t3;
    int segrows= ((e==0)?n0:(e==1)?n1:(e==2)?n2:n3)*256;
    int wbase = 0;
    for (int i = 0; i < wv; ++i) wbase += wsum[i];
    int myoff = mybase + wbase + sc - mysel;
    #pragma unroll
    for (int i = 0; i < 16; ++i){
        int j = base + i;
        if (expi[j] == e){
            tokl[myoff]  = j >> 1;
            slotof[j] = myoff;
            myoff++;
        }
    }
    for (int i = cnt_e + tid; i < segrows; i += 1024) tokl[mybase + i] = 0;
    if (e == 0 && tid == 0){
        tbase[0]=0; tbase[1]=tb1; tbase[2]=tb2; tbase[3]=tb3; tbase[4]=tb4;
    }
}

// =================== unified GEMM: 128x128x64, 4 waves, 2 blocks/CU =========
// EXACT R13 hot loop (best verified: 441 us). Grouped bands of 8 nt,
// mt-major within a band, for BOTH GEMMs.

#define G_MFMA(RA, RB, NB) \
  _Pragma("unroll") for (int mf_ = 0; mf_ < 4; ++mf_) \
    _Pragma("unroll") for (int nf_ = 0; nf_ < 2; ++nf_) \
      _Pragma("unroll") for (int ks_ = 0; ks_ < 2; ++ks_) \
        acc[mf_][NB+nf_] = __builtin_amdgcn_mfma_f32_16x16x32_f16( \
            RA[mf_][ks_], RB[nf_][ks_], acc[mf_][NB+nf_], 0, 0, 0)

#define G_LDA(CUR) \
  _Pragma("unroll") for (int mf_ = 0; mf_ < 4; ++mf_) \
    _Pragma("unroll") for (int ks_ = 0; ks_ < 2; ++ks_) \
      rA[mf_][ks_] = *(const f16x8*)(smem + (CUR)*32768 + (rbA[mf_] ^ (ks_<<6)))

#define G_LDB(DST, NB, CUR) \
  _Pragma("unroll") for (int nf_ = 0; nf_ < 2; ++nf_) \
    _Pragma("unroll") for (int ks_ = 0; ks_ < 2; ++ks_) \
      DST[nf_][ks_] = *(const f16x8*)(smem + (CUR)*32768 + (rbB[NB+nf_] ^ (ks_<<6)))

#define STG_A(Q, KT) do{ \
    GLDS16(pA[0] + (size_t)(KT)*64, smem + (Q)*32768 + dA0); \
    GLDS16(pA[1] + (size_t)(KT)*64, smem + (Q)*32768 + dA1); \
    GLDS16(pA[2] + (size_t)(KT)*64, smem + (Q)*32768 + dA2); \
    GLDS16(pA[3] + (size_t)(KT)*64, smem + (Q)*32768 + dA3); }while(0)
#define STG_B(Q, KT, G) do{ \
    GLDS16(pB[G][0] + (size_t)(KT)*64, smem + (Q)*32768 + 16384 + dB[G][0]); \
    GLDS16(pB[G][1] + (size_t)(KT)*64, smem + (Q)*32768 + 16384 + dB[G][1]); }while(0)

template<int KDIM, int NDIM, bool G1>
__global__ __launch_bounds__(256, 2)
void k_gemm(const _Float16* __restrict__ Aglob, const _Float16* __restrict__ Bglob,
            const float* __restrict__ b1, const int* __restrict__ tokl,
            const int* __restrict__ tb, _Float16* __restrict__ Cout)
{
    extern __shared__ char smem[];
    const int NT = NDIM/128;                     // 32 (g1) / 8 (g2), mult of 8
    const int M2 = 2*MAXT;                       // 136 m-tiles of 128 rows
    const int nwg = M2*NT;                       // div by 8
    const int logical = ((int)blockIdx.x & 7)*(nwg>>3) + ((int)blockIdx.x >> 3);
    const int band = logical / (M2*8);
    const int rr_  = logical % (M2*8);
    const int mt = rr_ >> 3, nt = band*8 + (rr_ & 7);
    if (mt >= 2*tb[4]) return;
    const int e = (mt >= 2*tb[1]) + (mt >= 2*tb[2]) + (mt >= 2*tb[3]);
    const int tid = (int)threadIdx.x;
    const int ln = tid & 63, wv = tid >> 6;      // 4 waves
    const int wr2 = wv >> 1, wc2 = wv & 1;       // 2M x 2N
    const int lr = ln & 15, lk = ln >> 4;
    const int NK = KDIM/64;

    const _Float16* pA[4];
    const _Float16* pB[2][2];
    int dB[2][2];
    #pragma unroll
    for (int l = 0; l < 4; ++l){
        const int fl = l*256 + wv*64 + ln;       // chunk 0..1023
        const int r_ = fl >> 3;                  // row 0..127
        const int c  = fl & 7;
        const int csw = (c ^ (r_ & 7)) * 8;
        size_t arow;
        if constexpr (G1) arow = (size_t)tokl[mt*128 + r_];
        else              arow = (size_t)(mt*128 + r_);
        pA[l] = Aglob + arow*KDIM + csw;
    }
    const int dA0 = (0*256 + wv*64)*16, dA1 = (1*256 + wv*64)*16;
    const int dA2 = (2*256 + wv*64)*16, dA3 = (3*256 + wv*64)*16;
    #pragma unroll
    for (int g = 0; g < 2; ++g)
      #pragma unroll
      for (int l = 0; l < 2; ++l){
        const int fl = l*256 + wv*64 + ln;       // 0..511 within group
        const int r0 = fl >> 3;                  // 0..63
        const int c  = fl & 7;
        const int rowB = (r0 & 31) + ((r0 >> 5) << 6) + g*32;
        const int csw = (c ^ (rowB & 7)) * 8;
        pB[g][l] = Bglob + ((size_t)e*NDIM + nt*128 + rowB)*KDIM + csw;
        const int r00 = (l*256 + wv*64) >> 3;    // lane-0 chunk row
        dB[g][l] = ((r00 & 31) + ((r00 >> 5) << 6) + g*32) * 128;
      }

    int rbA[4], rbB[4];
    #pragma unroll
    for (int mf = 0; mf < 4; ++mf){
        int row = wr2*64 + mf*16 + lr;
        rbA[mf] = row*128 + ((lk*16) ^ ((row&7)<<4));
    }
    #pragma unroll
    for (int nf = 0; nf < 4; ++nf){
        int row = wc2*64 + nf*16 + lr;
        rbB[nf] = 16384 + row*128 + ((lk*16) ^ ((row&7)<<4));
    }

    f32x4 acc[4][4];
    #pragma unroll
    for (int i = 0; i < 4; ++i)
        #pragma unroll
        for (int j = 0; j < 4; ++j) acc[i][j] = (f32x4){0.f,0.f,0.f,0.f};
    f16x8 rA[4][2], rB0[2][2], rB1[2][2];

    // prologue FIFO: AB0(0)6, B1(0)2, AB0(1)6 ; confirm AB0(0)
    STG_A(0,0); STG_B(0,0,0);
    STG_B(0,0,1);
    STG_A(1,1); STG_B(1,1,0);
    VMCNTN(8);
    BARRIER();

    for (int t = 0; t < NK; ++t){
        const int cur = t & 1;
        // P1: read A,B0(t); stage B1(t+1)->cur^1; pair confirms B1(t)
        G_LDA(cur); G_LDB(rB0, 0, cur);
        if (t+1 < NK){ STG_B(cur^1, t+1, 1); VMCNTN(8); } else { VMCNTN(0); }
        BARRIER();
        __builtin_amdgcn_s_setprio(1); G_MFMA(rA, rB0, 0); __builtin_amdgcn_s_setprio(0);
        BARRIER();
        // P2: read B1(t); stage A,B0(t+2)->cur; pair confirms AB0(t+1)
        G_LDB(rB1, 2, cur);
        if (t+2 < NK){ STG_A(cur, t+2); STG_B(cur, t+2, 0); VMCNTN(8); }
        else if (t+1 < NK){ VMCNTN(2); }
        else { VMCNTN(0); }
        BARRIER();
        __builtin_amdgcn_s_setprio(1); G_MFMA(rA, rB1, 2); __builtin_amdgcn_s_setprio(0);
        BARRIER();
    }

    if constexpr (G1){
        float bv[4];
        #pragma unroll
        for (int nf = 0; nf < 4; ++nf)
            bv[nf] = b1[e*NDIM + nt*128 + wc2*64 + nf*16 + lr];
        #pragma unroll
        for (int mf = 0; mf < 4; ++mf){
            int row = mt*128 + wr2*64 + mf*16 + lk*4;
            #pragma unroll
            for (int nf = 0; nf < 4; ++nf){
                int col = nt*128 + wc2*64 + nf*16 + lr;
                #pragma unroll
                for (int r = 0; r < 4; ++r)
                    Cout[(size_t)(row+r)*NDIM + col] = (_Float16)gelu_tanh(acc[mf][nf][r] + bv[nf]);
            }
        }
    } else {
        #pragma unroll
        for (int mf = 0; mf < 4; ++mf){
            int row = mt*128 + wr2*64 + mf*16 + lk*4;
            #pragma unroll
            for (int nf = 0; nf < 4; ++nf){
                int col = nt*128 + wc2*64 + nf*16 + lr;
                #pragma unroll
                for (int r = 0; r < 4; ++r)
                    Cout[(size_t)(row+r)*NDIM + col] = (_Float16)acc[mf][nf][r];
            }
        }
    }
}

// ---------------- final: out = csum + g0*(y0-c'0) + g1*(y1-c'1) -------------
__global__ void k_final(const int* __restrict__ expi, const float* __restrict__ gatev,
                        const int* __restrict__ slotof, const _Float16* __restrict__ ybuf,
                        const float* __restrict__ cprime, const float* __restrict__ csum,
                        float* __restrict__ out){
    int i = blockIdx.x*256 + threadIdx.x;
    int t = i >> 8;
    int dq = i & 255;
    int e0 = expi[2*t], e1 = expi[2*t+1];
    float g0 = gatev[2*t], g1 = gatev[2*t+1];
    int s0 = slotof[2*t], s1 = slotof[2*t+1];
    const float4* cp = (const float4*)cprime;
    float4 cs = ((const float4*)csum)[dq];
    float4 c0 = cp[e0*256 + dq], c1 = cp[e1*256 + dq];
    f16x4 y0 = ((const f16x4*)ybuf)[(size_t)s0*256 + dq];
    f16x4 y1 = ((const f16x4*)ybuf)[(size_t)s1*256 + dq];
    float4 r;
    r.x = cs.x + g0*((float)y0[0] - c0.x) + g1*((float)y1[0] - c1.x);
    r.y = cs.y + g0*((float)y0[1] - c0.y) + g1*((float)y1[1] - c1.y);
    r.z = cs.z + g0*((float)y0[2] - c0.z) + g1*((float)y1[2] - c1.z);
    r.w = cs.w + g0*((float)y0[3] - c0.w) + g1*((float)y1[3] - c1.w);
    ((float4*)out)[i] = r;
}

extern "C" void kernel_launch(void* const* d_in, const int* in_sizes, int n_in,
                              void* d_out, int out_size, void* d_ws, size_t ws_size,
                              hipStream_t stream){
    const float* x  = (const float*)d_in[0];
    const float* w1 = (const float*)d_in[1];
    const float* b1 = (const float*)d_in[2];
    const float* w2 = (const float*)d_in[3];
    const float* b2 = (const float*)d_in[4];
    const float* wr = (const float*)d_in[5];
    const float* br = (const float*)d_in[6];
    float* out = (float*)d_out;

    char* ws = (char*)d_ws;
    size_t o = 0;
    auto take = [&](size_t bytes)->char*{
        char* p = ws + o;
        o = (o + bytes + 255) & ~(size_t)255;
        return p;
    };
    _Float16* xb    = (_Float16*)take((size_t)N_TOK*DIM*2);        // 16.8 MB
    _Float16* w1t   = (_Float16*)take((size_t)NEXP*HID*DIM*2);     // 33.5 MB
    _Float16* w2t   = (_Float16*)take((size_t)NEXP*HID*DIM*2);     // 33.5 MB
    _Float16* hbuf  = (_Float16*)take((size_t)NSLOT*HID*2);        // 142.6 MB
    _Float16* ybuf  = (_Float16*)take((size_t)NSLOT*DIM*2);        // 35.7 MB
    float*    gb1   = (float*)take((size_t)NEXP*HID*4);
    float*    cprime= (float*)take((size_t)NEXP*DIM*4);
    float*    csum  = (float*)take((size_t)DIM*4);
    int*      tbase = (int*)take(64);
    int*      expi  = (int*)take((size_t)N_TOK*2*4);
    float*    gatev = (float*)take((size_t)N_TOK*2*4);
    int*      slotof= (int*)take((size_t)N_TOK*2*4);
    int*      tokl  = (int*)take((size_t)NSLOT*4);
    (void)ws_size; (void)in_sizes; (void)n_in; (void)out_size;

    hipFuncSetAttribute(reinterpret_cast<const void*>(&k_gemm<DIM, HID, true>),
                        hipFuncAttributeMaxDynamicSharedMemorySize, 65536);
    hipFuncSetAttribute(reinterpret_cast<const void*>(&k_gemm<HID, DIM, false>),
                        hipFuncAttributeMaxDynamicSharedMemorySize, 65536);

    hipLaunchKernelGGL(k_transpose_all, dim3(32768), dim3(256), 0, stream, w1, w2, w1t, w2t);
    hipLaunchKernelGGL(k_gb1, dim3(NEXP*HID/256), dim3(256), 0, stream, b1, gb1, NEXP*HID);
    hipLaunchKernelGGL(k_cprime_w, dim3(NEXP*DIM/4), dim3(256), 0, stream, w2t, gb1, cprime);
    hipLaunchKernelGGL(k_csum, dim3(DIM/256), dim3(256), 0, stream, cprime, b2, csum);
    hipLaunchKernelGGL(k_route, dim3(N_TOK/4), dim3(256), 0, stream, x, wr, br, xb, expi, gatev);
    hipLaunchKernelGGL(k_compact, dim3(NEXP), dim3(1024), 0, stream, expi, gatev, tbase, tokl, slotof);
    hipLaunchKernelGGL((k_gemm<DIM, HID, true>), dim3(2*MAXT*(HID/128)), dim3(256), 65536, stream,
                       xb, w1t, b1, tokl, tbase, hbuf);
    hipLaunchKernelGGL((k_gemm<HID, DIM, false>), dim3(2*MAXT*(DIM/128)), dim3(256), 65536, stream,
                       hbuf, w2t, b1, tokl, tbase, ybuf);
    hipLaunchKernelGGL(k_final, dim3(N_TOK*DIM/4/256), dim3(256), 0, stream,
                       expi, gatev, slotof, ybuf, cprime, csum, out);
}